// Round 6
// baseline (192.688 us; speedup 1.0000x reference)
//
#include <hip/hip_runtime.h>
#include <hip/hip_bf16.h>

#define NN   8192
#define DIN  512
#define DOUT 256

typedef __attribute__((ext_vector_type(8)))  short s16x8;   // 8 bf16 (A/B frag)
typedef __attribute__((ext_vector_type(16))) float f32x16;  // 32x32 C/D frag

static __device__ __forceinline__ unsigned short f2bf(float f) {
    union { float f; unsigned u; } v; v.f = f;
    unsigned r = v.u + 0x7fffu + ((v.u >> 16) & 1u);   // RNE
    return (unsigned short)(r >> 16);
}

static __device__ __forceinline__ void gload_lds16(const void* g, void* l) {
    __builtin_amdgcn_global_load_lds(
        (const __attribute__((address_space(1))) unsigned int*)g,
        (__attribute__((address_space(3))) unsigned int*)l, 16, 0, 0);
}

// ---------------- Kernel 1: Wh/WhT + src/dst (phase 1)  +  adj->bitmask (phase 2) ----
// Bitmask layout: byte index = row*1024 + ks*256 + kb*32 + t   (ks:2 kb:3 t:5 bits)
// so the attn builder thread (row, ks, kb) owns 32 CONTIGUOUS bytes, one per step t.
__global__ __launch_bounds__(256) void k_whm(const float* __restrict__ feat,
                                             const float* __restrict__ W,
                                             const float* __restrict__ a,
                                             const int* __restrict__ adj,
                                             unsigned short* __restrict__ WhT,
                                             float* __restrict__ src,
                                             float* __restrict__ dst,
                                             unsigned char* __restrict__ bits) {
    __shared__ float lf[16 * DIN];                 // 32 KB
    __shared__ float red[2][4][16];
    const int tid = threadIdx.x;
    const int i0  = blockIdx.x * 16;
    const int w   = tid >> 6, lane = tid & 63;

    const float4* fsrc = (const float4*)(feat + (size_t)i0 * DIN);
    float4* fdst = (float4*)lf;
    #pragma unroll
    for (int q = 0; q < 8; ++q) fdst[tid + q * 256] = fsrc[tid + q * 256];
    __syncthreads();

    const int c = tid;
    float outs[16];
    #pragma unroll
    for (int r = 0; r < 16; ++r) outs[r] = 0.f;

    for (int k = 0; k < DIN; k += 4) {
        float w0 = W[(k + 0) * DOUT + c];
        float w1 = W[(k + 1) * DOUT + c];
        float w2 = W[(k + 2) * DOUT + c];
        float w3 = W[(k + 3) * DOUT + c];
        #pragma unroll
        for (int r = 0; r < 16; ++r) {
            float4 f = *(const float4*)&lf[r * DIN + k];   // broadcast read
            outs[r] = fmaf(f.x, w0, fmaf(f.y, w1, fmaf(f.z, w2, fmaf(f.w, w3, outs[r]))));
        }
    }

    unsigned short tb[16];
    #pragma unroll
    for (int r = 0; r < 16; ++r) tb[r] = f2bf(outs[r]);
    uint4* wt = (uint4*)(WhT + (size_t)c * NN + i0);
    wt[0] = *(uint4*)&tb[0];
    wt[1] = *(uint4*)&tb[8];

    // fused src/dst = Wh @ a halves (fp32, exact Wh from registers)
    const float as_ = a[c], ad_ = a[DOUT + c];
    #pragma unroll
    for (int r = 0; r < 16; ++r) {
        float s = outs[r] * as_;
        float d = outs[r] * ad_;
        #pragma unroll
        for (int off = 32; off; off >>= 1) {
            s += __shfl_xor(s, off);
            d += __shfl_xor(d, off);
        }
        if (lane == 0) { red[0][w][r] = s; red[1][w][r] = d; }
    }
    __syncthreads();
    if (tid < 16)
        src[i0 + tid] = red[0][0][tid] + red[0][1][tid] + red[0][2][tid] + red[0][3][tid];
    else if (tid < 32) {
        int r = tid - 16;
        dst[i0 + r] = red[1][0][r] + red[1][1][r] + red[1][2][r] + red[1][3][r];
    }

    // ---- phase 2: adj -> bitmask, pure grid-stride HBM stream (no sync needed) ----
    const size_t gbase = (size_t)blockIdx.x * 256 + tid;    // byte index stride 131072
    for (int it = 0; it < 64; ++it) {
        const size_t g = gbase + (size_t)it * 131072;       // 0 .. 8.4M bytes
        const int row = (int)(g >> 10);
        const int b   = (int)(g & 1023);
        const int s_  = b >> 8, t_ = (b >> 3) & 31, kb_ = b & 7;
        const int4 v0 = *(const int4*)(adj + g * 8);
        const int4 v1 = *(const int4*)(adj + g * 8 + 4);
        unsigned int m = (v0.x > 0 ? 1u : 0u) | (v0.y > 0 ? 2u : 0u) |
                         (v0.z > 0 ? 4u : 0u) | (v0.w > 0 ? 8u : 0u) |
                         (v1.x > 0 ? 16u : 0u) | (v1.y > 0 ? 32u : 0u) |
                         (v1.z > 0 ? 64u : 0u) | (v1.w > 0 ? 128u : 0u);
        bits[(size_t)row * 1024 + s_ * 256 + kb_ * 32 + t_] = (unsigned char)m;
    }
}

// ---------------- Kernel 2: masked-exp GEMM from bitmask, single barrier/step --------
// grid = 128 rt x 4 ks = 512 blocks (2/CU, 80 KB LDS). block = 512 thr = 8 waves.
// BM=64 x 256 cols; wave 64x32 (2 m-tiles x 4 ksub, 32x32x16 MFMA). No HBM in loop:
// bits (L1), dst (L1), WhT (L2). Dbuf Pl AND Bs -> one s_barrier per step is race-free:
//   iter T (post-barrier): stage B(T+1)->Bs[T+1&1] (Bs[T-1&1] readers done at barrier),
//   MFMA(T) from Pl/Bs[T&1], build P(T+1)->Pl[T+1&1], vmcnt0+lgkm0, barrier.
#define STEP5(T, CUR)                                                                    \
{                                                                                        \
    {   /* stage B(T+1) into Bs[CUR^1]; clamp keeps last iter harmless */                \
        const int tn_ = ((T) < 31) ? (T) + 1 : 31;                                       \
        const size_t gkb_ = (size_t)(kb0 + tn_ * 64) * 2;                                \
        _Pragma("unroll")                                                                \
        for (int q = 0; q < 4; ++q)                                                      \
            gload_lds16((const char*)WhT + (size_t)colB[q] * (NN * 2) + gkb_ + kbB[q],   \
                        Bs[(CUR) ^ 1] + (q * 512 + tid) * 16);                           \
    }                                                                                    \
    /* MFMA(T) from Pl[CUR] + Bs[CUR] */                                                 \
    _Pragma("unroll")                                                                    \
    for (int ks4 = 0; ks4 < 4; ++ks4) {                                                  \
        const int kbyte_ = ks4 * 32 + lhi * 16;                                          \
        const int colg_  = c0w + l31;                                                    \
        s16x8 bfv_ = *(const s16x8*)(Bs[CUR] + colg_ * 128 +                             \
                                     (kbyte_ ^ ((colg_ & 7) << 4)));                     \
        _Pragma("unroll")                                                                \
        for (int mt = 0; mt < 2; ++mt) {                                                 \
            const int row_ = mt * 32 + l31;                                              \
            s16x8 afv_ = *(const s16x8*)(Pl[CUR] + row_ * 128 +                          \
                                         (kbyte_ ^ ((row_ & 7) << 4)));                  \
            acc[mt] = __builtin_amdgcn_mfma_f32_32x32x16_bf16(afv_, bfv_, acc[mt], 0, 0, 0); \
        }                                                                                \
    }                                                                                    \
    if ((T) < 31) {   /* build P(T+1) -> Pl[CUR^1] */                                    \
        const unsigned int m8_ = browp[(T) + 1];                                         \
        float4 d0_ = *(const float4*)(dstp + ((T) + 1) * 64);                            \
        float4 d1_ = *(const float4*)(dstp + ((T) + 1) * 64 + 4);                        \
        const float dd_[8] = {d0_.x, d0_.y, d0_.z, d0_.w, d1_.x, d1_.y, d1_.z, d1_.w};   \
        s16x8 pw_;                                                                       \
        _Pragma("unroll")                                                                \
        for (int jj = 0; jj < 8; ++jj) {                                                 \
            float x_ = si + dd_[jj];                                                     \
            x_ = fmaxf(x_, 0.2f * x_);                  /* leaky_relu 0.2 */             \
            float p_ = (m8_ >> jj) & 1u ? __expf(x_) : 0.f;  /* bounded: no max-sub */   \
            den += p_;                                                                   \
            pw_[jj] = (short)f2bf(p_);                                                   \
        }                                                                                \
        *(s16x8*)(Pl[(CUR) ^ 1] + pbyte) = pw_;                                          \
    }                                                                                    \
    asm volatile("s_waitcnt vmcnt(0) lgkmcnt(0)" ::: "memory");                          \
    __builtin_amdgcn_s_barrier();                                                        \
}

__global__ __launch_bounds__(512, 4) void k_attn5(const unsigned char* __restrict__ bits,
                                                  const unsigned short* __restrict__ WhT,
                                                  const float* __restrict__ src,
                                                  const float* __restrict__ dstg,
                                                  float* __restrict__ denp,
                                                  float* __restrict__ part) {
    __shared__ __attribute__((aligned(16))) char Bs[2][32768];  // WhT slab [256 col][64 k] swz
    __shared__ __attribute__((aligned(16))) char Pl[2][8192];   // P slab  [64 row][64 k] swz

    const int tid  = threadIdx.x;
    const int lane = tid & 63;
    const int w    = tid >> 6;
    const int l31  = lane & 31, lhi = lane >> 5;
    const int c0w  = w * 32;

    const int rt  = blockIdx.x & 127;
    const int ks  = blockIdx.x >> 7;           // 0..3
    const int kb0 = ks * 2048;

    // builder role: row r, k-block kb (8 consecutive k per step)
    const int r  = tid >> 3, kb = tid & 7;
    const int gr = rt * 64 + r;
    const float si = src[gr];
    const unsigned char* browp = bits + (size_t)gr * 1024 + ks * 256 + kb * 32;
    const float* dstp = dstg + kb0 + kb * 8;
    const int pbyte = r * 128 + ((kb * 16) ^ ((r & 7) << 4));

    // B staging maps (pre-swizzled global source, linear LDS dest)
    int colB[4], kbB[4];
    #pragma unroll
    for (int q = 0; q < 4; ++q) {
        int chunk = q * 512 + tid;
        colB[q] = chunk >> 3;
        kbB[q]  = ((chunk & 7) * 16) ^ ((colB[q] & 7) << 4);
    }

    f32x16 acc[2];
    #pragma unroll
    for (int mt = 0; mt < 2; ++mt)
        #pragma unroll
        for (int e = 0; e < 16; ++e) acc[mt][e] = 0.f;
    float den = 0.f;

    // prologue: stage B(0) -> Bs[0]; build P(0) -> Pl[0]
    #pragma unroll
    for (int q = 0; q < 4; ++q)
        gload_lds16((const char*)WhT + (size_t)colB[q] * (NN * 2) + (size_t)kb0 * 2 + kbB[q],
                    Bs[0] + (q * 512 + tid) * 16);
    {
        const unsigned int m8 = browp[0];
        float4 d0 = *(const float4*)(dstp);
        float4 d1 = *(const float4*)(dstp + 4);
        const float dd[8] = {d0.x, d0.y, d0.z, d0.w, d1.x, d1.y, d1.z, d1.w};
        s16x8 pw;
        #pragma unroll
        for (int jj = 0; jj < 8; ++jj) {
            float x = si + dd[jj];
            x = fmaxf(x, 0.2f * x);
            float p = (m8 >> jj) & 1u ? __expf(x) : 0.f;
            den += p;
            pw[jj] = (short)f2bf(p);
        }
        *(s16x8*)(Pl[0] + pbyte) = pw;
    }
    asm volatile("s_waitcnt vmcnt(0) lgkmcnt(0)" ::: "memory");
    __builtin_amdgcn_s_barrier();

    for (int tt = 0; tt < 16; ++tt) {
        STEP5(2 * tt,     0);
        STEP5(2 * tt + 1, 1);
    }

    // denominator: reduce over the 8 kb lanes (lane bits 0..2)
    den += __shfl_xor(den, 1);
    den += __shfl_xor(den, 2);
    den += __shfl_xor(den, 4);
    if ((tid & 7) == 0) denp[(size_t)ks * NN + gr] = den;

    // epilogue: C/D layout (m74/m101): col = lane&31, row = (reg&3)+8*(reg>>2)+4*lhi
    float* pp = part + (size_t)ks * (NN * DOUT);
    #pragma unroll
    for (int mt = 0; mt < 2; ++mt) {
        #pragma unroll
        for (int e = 0; e < 16; ++e) {
            const int row = rt * 64 + mt * 32 + (e & 3) + 8 * (e >> 2) + 4 * lhi;
            pp[(size_t)row * DOUT + c0w + l31] = acc[mt][e];
        }
    }
}

// ---------------- Kernel 3: out = elu( (sum_ks num) / (sum_ks den) ) -----------------
__global__ __launch_bounds__(256) void k_finish2(const float* __restrict__ part,
                                                 const float* __restrict__ denp,
                                                 float* __restrict__ out) {
    const int idx = blockIdx.x * 256 + threadIdx.x;   // float4 units
    const int row = idx >> 6;                          // 64 float4 per row
    float den = denp[row] + denp[NN + row] + denp[2 * NN + row] + denp[3 * NN + row];
    float rv = den > 0.f ? 1.f / den : 0.f;
    const int st = NN * DOUT / 4;
    const float4* p = (const float4*)part;
    float4 va = p[idx], vb = p[idx + st], vc = p[idx + 2 * st], vd = p[idx + 3 * st];
    float4 s;
    s.x = (va.x + vb.x + vc.x + vd.x) * rv;
    s.y = (va.y + vb.y + vc.y + vd.y) * rv;
    s.z = (va.z + vb.z + vc.z + vd.z) * rv;
    s.w = (va.w + vb.w + vc.w + vd.w) * rv;
    s.x = s.x > 0.f ? s.x : expm1f(s.x);
    s.y = s.y > 0.f ? s.y : expm1f(s.y);
    s.z = s.z > 0.f ? s.z : expm1f(s.z);
    s.w = s.w > 0.f ? s.w : expm1f(s.w);
    ((float4*)out)[idx] = s;
}

extern "C" void kernel_launch(void* const* d_in, const int* in_sizes, int n_in,
                              void* d_out, int out_size, void* d_ws, size_t ws_size,
                              hipStream_t stream) {
    const float* feat = (const float*)d_in[0];
    const int*   adj  = (const int*)d_in[1];
    const float* W    = (const float*)d_in[2];
    const float* a    = (const float*)d_in[3];
    float* out = (float*)d_out;

    char* ws = (char*)d_ws;
    unsigned short* WhT  = (unsigned short*)ws;               // 4 MB
    float*          src  = (float*)(ws + 4194304);            // 32 KB
    float*          dst  = (float*)(ws + 4227072);            // 32 KB
    float*          denp = (float*)(ws + 4259840);            // 128 KB
    unsigned char*  bits = (unsigned char*)(ws + 4390912);    // 8 MB
    float*          part = (float*)(ws + 12779520);           // 32 MB (4 x 8 MB)

    k_whm    <<<512,  256, 0, stream>>>(feat, W, a, adj, WhT, src, dst, bits);
    k_attn5  <<<512,  512, 0, stream>>>(bits, WhT, src, dst, denp, part);
    k_finish2<<<2048, 256, 0, stream>>>(part, denp, out);
}